// Round 2
// baseline (164.103 us; speedup 1.0000x reference)
//
#include <hip/hip_runtime.h>

// MRPCEN: multi-rate PCEN.
//   x: (B=16, F=128, T=4096) f32; alpha_log/delta_log/r_log: (F,) f32
//   out: (B, 4, F, T) f32
// m[b,f,0]=x[b,f,0]; m[t]=(1-s)m[t-1]+s x[t]  (4 s-values, compile-time consts)
// out = (x*(EPS+m)^(-alpha) + delta)^r - delta^r
//
// Parallel linear scan: block of 1024 threads per (b,f) row, thread i owns
// t=4i..4i+3 (float4-coalesced load AND store). Decoupled scan: local 4-step
// recurrence (zero init) -> wave Hillis-Steele scan with decay (1-s)^4 ->
// cross-wave combine through LDS with ONE barrier (all 4 s batched).
// Initial condition folded in by seeding carry with x[0] ((1-s)x0+s*x0=x0).
//
// NOTE: no <math.h> include — glibc's __MATHCALL declares __exp2f etc. and
// collides with HIP device intrinsics. Use __builtin_amdgcn_* directly.

#define EPS_C 1e-5f

__device__ __forceinline__ float fexp2(float v) { return __builtin_amdgcn_exp2f(v); }
__device__ __forceinline__ float flog2(float v) { return __builtin_amdgcn_logf(v); }
__device__ __forceinline__ float fpow(float a, float b) { return fexp2(b * flog2(a)); }
__device__ __forceinline__ float fexp(float v) { return fexp2(v * 1.44269504f); }

__global__ __launch_bounds__(1024)
void pcen_kernel(const float* __restrict__ x,
                 const float* __restrict__ alpha_log,
                 const float* __restrict__ delta_log,
                 const float* __restrict__ r_log,
                 float* __restrict__ out)
{
    const int row  = blockIdx.x;          // b*128 + f
    const int f    = row & 127;
    const int b    = row >> 7;
    const int tid  = threadIdx.x;         // 0..1023
    const int lane = tid & 63;
    const int w    = tid >> 6;            // wave id 0..15

    __shared__ float wq[4][16];           // per-s, per-wave inclusive scan tails
    __shared__ float sh_x0;

    const float4* __restrict__ xrow4 = (const float4*)(x + (size_t)row * 4096);
    float4 xv = xrow4[tid];
    if (tid == 0) sh_x0 = xv.x;

    // s-values from module constants (const-folded by the compiler)
    const float Tv[4] = {0.015f, 0.06f, 0.25f, 1.0f};
    float s_arr[4], omn_arr[4];
#pragma unroll
    for (int i = 0; i < 4; ++i) {
        float t  = Tv[i] * 86.1328125f;   // 44100/512
        float t2 = t * t;
        float s  = (__builtin_sqrtf(1.0f + 4.0f * t2) - 1.0f) / (2.0f * t2);
        s_arr[i]   = s;
        omn_arr[i] = 1.0f - s;
    }

    // Phase 1: per-s local recurrence + wave scan (no barrier yet)
    float qxv[4];
#pragma unroll
    for (int i = 0; i < 4; ++i) {
        const float s = s_arr[i], omn = omn_arr[i];
        // local 4-element recurrence, zero initial state
        float p = s * xv.x;
        p = fmaf(omn, p, s * xv.y);
        p = fmaf(omn, p, s * xv.z);
        p = fmaf(omn, p, s * xv.w);
        // wave-level inclusive scan of segment outputs, segment decay D4=omn^4
        float q = p;
        float c = omn * omn; c = c * c;   // omn^4
#pragma unroll
        for (int k = 0; k < 6; ++k) {
            int d = 1 << k;
            float tsh = __shfl_up(q, d);
            if (lane >= d) q = fmaf(c, tsh, q);
            c = c * c;
        }
        float qx = __shfl_up(q, 1);       // within-wave exclusive
        if (lane == 0) qx = 0.0f;
        qxv[i] = qx;
        if (lane == 63) wq[i][w] = q;
    }
    __syncthreads();                       // the only barrier

    // Per-F parameters (block-uniform -> scalarized)
    const float al = alpha_log[f], dl = delta_log[f], rl = r_log[f];
    const float nalpha  = -fexp(al);
    const float delta   =  fexp(dl);
    const float r       =  fexp(rl);
    const float delta_r =  fexp(r * dl);  // delta^r = exp(r*log(delta))

    const float x0 = sh_x0;
    float4* __restrict__ out4 = (float4*)out;

#pragma unroll
    for (int i = 0; i < 4; ++i) {
        const float s = s_arr[i], omn = omn_arr[i];
        const float l2omn = flog2(omn);
        const float Dw = fexp2(256.0f * l2omn);      // omn^256 (wave decay)
        // carry entering this wave; seed with M(-1)=x0 so m[0]=x[0] exactly
        float Q = x0;
        for (int v = 0; v < w; ++v) Q = fmaf(Dw, Q, wq[i][v]);
        // carry entering this thread's segment
        const float dl4 = fexp2((float)(4 * lane) * l2omn); // omn^(4*lane)
        const float E = fmaf(dl4, Q, qxv[i]);
        // replay recurrence from true carry
        float m0 = fmaf(omn, E,  s * xv.x);
        float m1 = fmaf(omn, m0, s * xv.y);
        float m2 = fmaf(omn, m1, s * xv.z);
        float m3 = fmaf(omn, m2, s * xv.w);
        // pcen = (x*(EPS+m)^(-alpha) + delta)^r - delta^r
        float4 o;
        o.x = fpow(fmaf(xv.x, fpow(EPS_C + m0, nalpha), delta), r) - delta_r;
        o.y = fpow(fmaf(xv.y, fpow(EPS_C + m1, nalpha), delta), r) - delta_r;
        o.z = fpow(fmaf(xv.z, fpow(EPS_C + m2, nalpha), delta), r) - delta_r;
        o.w = fpow(fmaf(xv.w, fpow(EPS_C + m3, nalpha), delta), r) - delta_r;

        const size_t obase4 = ((size_t)((b * 4 + i) * 128 + f)) * 1024; // /4
        out4[obase4 + tid] = o;
    }
}

extern "C" void kernel_launch(void* const* d_in, const int* in_sizes, int n_in,
                              void* d_out, int out_size, void* d_ws, size_t ws_size,
                              hipStream_t stream) {
    const float* x  = (const float*)d_in[0];
    const float* al = (const float*)d_in[1];
    const float* dl = (const float*)d_in[2];
    const float* rl = (const float*)d_in[3];
    float* out = (float*)d_out;
    const int rows = in_sizes[0] / 4096;   // B*F = 2048
    pcen_kernel<<<rows, 1024, 0, stream>>>(x, al, dl, rl, out);
}